// Round 1
// baseline (187.098 us; speedup 1.0000x reference)
//
#include <hip/hip_runtime.h>
#include <math.h>

#define BLOCK 256

__global__ void zero_kernel(float* out) {
    if (threadIdx.x == 0 && blockIdx.x == 0) out[0] = 0.0f;
}

// Reference-faithful "sorted_poly_area": mean over valid pts, angle-sort
// (stable, invalid -> 1e9), invalid sorted slots replaced by sorted[0],
// shoelace, abs * 0.5. Rank-count + LDS scatter replaces argsort.
template <int NP>
__device__ __forceinline__ float sorted_poly_area(
    const float* px, const float* py, unsigned vmask, int cnt,
    float (*sx)[BLOCK], float (*sy)[BLOCK], int tid) {
    // masked mean (invalid entries excluded; matches pts * maskf sum / max(cnt,1))
    float sxs = 0.f, sys = 0.f;
#pragma unroll
    for (int j = 0; j < NP; ++j) {
        bool v = (vmask >> j) & 1u;
        sxs += v ? px[j] : 0.f;
        sys += v ? py[j] : 0.f;
    }
    float num = fmaxf((float)cnt, 1.f);
    float mx = sxs / num, my = sys / num;

    float ang[NP];
#pragma unroll
    for (int j = 0; j < NP; ++j) {
        bool v = (vmask >> j) & 1u;
        ang[j] = v ? atan2f(py[j] - my, px[j] - mx) : 1e9f;
    }

    // rank = # of keys strictly before this one under (angle, index) lex order.
    // k<j is compile-time: pair cost = 1 cmp + 1 add. Scatter into per-thread
    // LDS slots (slot-major layout -> bank = tid%32, conflict-free).
#pragma unroll
    for (int j = 0; j < NP; ++j) {
        int r = 0;
#pragma unroll
        for (int k = 0; k < NP; ++k) {
            if (k < j)      r += (ang[k] <= ang[j]) ? 1 : 0;
            else if (k > j) r += (ang[k] <  ang[j]) ? 1 : 0;
        }
        sx[r][tid] = px[j];
        sy[r][tid] = py[j];
    }

    // shoelace over sorted entries; slots >= cnt behave as sorted[0]
    float x0 = sx[0][tid], y0 = sy[0][tid];
    float acc = 0.f, xp = x0, yp = y0;
#pragma unroll
    for (int k = 1; k < NP; ++k) {
        float xc = sx[k][tid], yc = sy[k][tid];
        bool use = (k < cnt);
        xc = use ? xc : x0;
        yc = use ? yc : y0;
        acc += xp * yc - yp * xc;
        xp = xc; yp = yc;
    }
    acc += xp * y0 - yp * x0;
    return 0.5f * fabsf(acc);
}

__launch_bounds__(BLOCK)
__global__ void giou_kernel(const float* __restrict__ pred,
                            const float* __restrict__ target,
                            const float* __restrict__ weight,
                            float* __restrict__ out, int N) {
    __shared__ float sx[24][BLOCK];
    __shared__ float sy[24][BLOCK];

    int tid = threadIdx.x;
    long gi = (long)blockIdx.x * BLOCK + tid;
    int i = (gi < (long)N) ? (int)gi : (N - 1);

    float p[5], q[5];
#pragma unroll
    for (int j = 0; j < 5; ++j) p[j] = pred[i * 5 + j];
#pragma unroll
    for (int j = 0; j < 5; ++j) q[j] = target[i * 5 + j];
    float wgt = weight[i];

    const float dxs[4] = {0.5f, -0.5f, -0.5f, 0.5f};
    const float dys[4] = {0.5f, 0.5f, -0.5f, -0.5f};
    float c1x[4], c1y[4], c2x[4], c2y[4];
    {
        float cs = cosf(p[4]), sn = sinf(p[4]);
#pragma unroll
        for (int j = 0; j < 4; ++j) {
            float cx = dxs[j] * p[2], cy = dys[j] * p[3];
            c1x[j] = cx * cs - cy * sn + p[0];
            c1y[j] = cx * sn + cy * cs + p[1];
        }
    }
    {
        float cs = cosf(q[4]), sn = sinf(q[4]);
#pragma unroll
        for (int j = 0; j < 4; ++j) {
            float cx = dxs[j] * q[2], cy = dys[j] * q[3];
            c2x[j] = cx * cs - cy * sn + q[0];
            c2y[j] = cx * sn + cy * cs + q[1];
        }
    }

    float px[24], py[24];
    unsigned vmask = 0;
#pragma unroll
    for (int j = 0; j < 4; ++j) {
        px[j] = c1x[j];     py[j] = c1y[j];
        px[4 + j] = c2x[j]; py[4 + j] = c2y[j];
    }

    // m1: corners of box1 inside box2 (bits 0..3)
    {
        float ax = c2x[0], ay = c2y[0];
        float abx = c2x[1] - ax, aby = c2y[1] - ay;
        float adx = c2x[3] - ax, ady = c2y[3] - ay;
        float ab2 = abx * abx + aby * aby;
        float ad2 = adx * adx + ady * ady;
#pragma unroll
        for (int j = 0; j < 4; ++j) {
            float amx = c1x[j] - ax, amy = c1y[j] - ay;
            float pab = (amx * abx + amy * aby) / ab2;
            float pad = (amx * adx + amy * ady) / ad2;
            bool in = (pab > -1e-6f) && (pab < 1.f + 1e-6f) &&
                      (pad > -1e-6f) && (pad < 1.f + 1e-6f);
            vmask |= ((unsigned)in) << j;
        }
    }
    // m2: corners of box2 inside box1 (bits 4..7)
    {
        float ax = c1x[0], ay = c1y[0];
        float abx = c1x[1] - ax, aby = c1y[1] - ay;
        float adx = c1x[3] - ax, ady = c1y[3] - ay;
        float ab2 = abx * abx + aby * aby;
        float ad2 = adx * adx + ady * ady;
#pragma unroll
        for (int j = 0; j < 4; ++j) {
            float amx = c2x[j] - ax, amy = c2y[j] - ay;
            float pab = (amx * abx + amy * aby) / ab2;
            float pad = (amx * adx + amy * ady) / ad2;
            bool in = (pab > -1e-6f) && (pab < 1.f + 1e-6f) &&
                      (pad > -1e-6f) && (pad < 1.f + 1e-6f);
            vmask |= ((unsigned)in) << (4 + j);
        }
    }

    // edge-pair intersections (bits 8..23), idx = 8 + j*4 + k
#pragma unroll
    for (int j = 0; j < 4; ++j) {
        float x1 = c1x[j], y1 = c1y[j];
        float x2 = c1x[(j + 1) & 3], y2 = c1y[(j + 1) & 3];
#pragma unroll
        for (int k = 0; k < 4; ++k) {
            float x3 = c2x[k], y3 = c2y[k];
            float x4 = c2x[(k + 1) & 3], y4 = c2y[(k + 1) & 3];
            float den = (x2 - x1) * (y4 - y3) - (y2 - y1) * (x4 - x3);
            float dens = (den == 0.f) ? 1.f : den;
            float t = ((x3 - x1) * (y4 - y3) - (y3 - y1) * (x4 - x3)) / dens;
            float u = ((x3 - x1) * (y2 - y1) - (y3 - y1) * (x2 - x1)) / dens;
            bool m = (den != 0.f) && (t > 0.f) && (t < 1.f) && (u > 0.f) && (u < 1.f);
            int idx = 8 + j * 4 + k;
            px[idx] = m ? (x1 + t * (x2 - x1)) : 0.f;
            py[idx] = m ? (y1 + t * (y2 - y1)) : 0.f;
            vmask |= ((unsigned)m) << idx;
        }
    }

    int cnt = __popc(vmask);
    float overlap = sorted_poly_area<24>(px, py, vmask, cnt, sx, sy, tid);

    float area1 = p[2] * p[3];
    float area2 = q[2] * q[3];
    float uni = area1 + area2 - overlap + 1e-6f;
    float iou = fmaxf(overlap / uni, 1e-6f);

    // enclose: 8 corner points, all valid
    float enc = sorted_poly_area<8>(px, py, 0xFFu, 8, sx, sy, tid);

    float giou = iou - (enc - uni) / enc;
    float loss = (1.f - giou) * wgt;
    if (gi >= (long)N) loss = 0.f;

    // wave-64 reduce, one atomic per wave
#pragma unroll
    for (int off = 32; off > 0; off >>= 1)
        loss += __shfl_down(loss, off, 64);
    if ((tid & 63) == 0)
        atomicAdd(out, loss * (1.0f / (float)N));
}

extern "C" void kernel_launch(void* const* d_in, const int* in_sizes, int n_in,
                              void* d_out, int out_size, void* d_ws, size_t ws_size,
                              hipStream_t stream) {
    const float* pred   = (const float*)d_in[0];
    const float* target = (const float*)d_in[1];
    const float* weight = (const float*)d_in[2];
    float* out = (float*)d_out;
    int N = in_sizes[0] / 5;

    zero_kernel<<<1, 64, 0, stream>>>(out);
    int nblocks = (N + BLOCK - 1) / BLOCK;
    giou_kernel<<<nblocks, BLOCK, 0, stream>>>(pred, target, weight, out, N);
}

// Round 2
// 176.868 us; speedup vs baseline: 1.0578x; 1.0578x over previous
//
#include <hip/hip_runtime.h>
#include <math.h>

#define BLOCK 256
#define NSLOT 16   // max valid polygon points: <=8 corners-inside + <=8 crossings

__global__ void zero_kernel(float* out) {
    if (threadIdx.x == 0 && blockIdx.x == 0) out[0] = 0.0f;
}

__device__ __forceinline__ float fast_rcp(float x) {
    return __builtin_amdgcn_rcpf(x);   // v_rcp_f32, ~1 ulp; mask/ordering paths only
}

// L1 "diamond" pseudo-angle: strictly monotone in atan2(y,x) over (-pi,pi].
// Range [-2,2]; (0,0) -> 0 (matches atan2(0,0)=0 ordering).
__device__ __forceinline__ float pseudo_angle(float x, float y) {
    float d = fabsf(x) + fabsf(y);
    float p = (d == 0.f) ? 1.f : x * fast_rcp(d);
    return (y < 0.f) ? (p - 1.f) : (1.f - p);
}

// Reference-faithful sorted_poly_area with rank-count sort + LDS scatter.
// NP = candidate points, NS = LDS slots actually needed (>= max possible cnt).
// Slot-major float2 layout: bank = (2*tid)%32 independent of rank -> conflict-free.
template <int NP, int NS>
__device__ __forceinline__ float sorted_area(
    const float* px, const float* py, unsigned vmask, int cnt,
    float mx, float my, float2 (*sb)[BLOCK], int tid) {

    float ang[NP];
#pragma unroll
    for (int j = 0; j < NP; ++j) {
        bool v = (vmask >> j) & 1u;
        ang[j] = v ? pseudo_angle(px[j] - mx, py[j] - my) : 1e9f;
    }

    // stable rank: # keys strictly before under (angle, index) lex order
#pragma unroll
    for (int j = 0; j < NP; ++j) {
        int r = 0;
#pragma unroll
        for (int k = 0; k < NP; ++k) {
            if (k < j)      r += (ang[k] <= ang[j]) ? 1 : 0;
            else if (k > j) r += (ang[k] <  ang[j]) ? 1 : 0;
        }
        // valid points always land at rank < cnt <= NS; invalid ones are never read
        if (r < NS) sb[r][tid] = make_float2(px[j], py[j]);
    }

    // shoelace over sorted valid points; slots >= cnt act as sorted[0]
    float2 s0 = sb[0][tid];
    float acc = 0.f, xp = s0.x, yp = s0.y;
#pragma unroll
    for (int k = 1; k < NS; ++k) {
        float2 c = sb[k][tid];
        bool use = (k < cnt);
        float xc = use ? c.x : s0.x;
        float yc = use ? c.y : s0.y;
        acc += xp * yc - yp * xc;
        xp = xc; yp = yc;
    }
    acc += xp * s0.y - yp * s0.x;
    return 0.5f * fabsf(acc);
}

__launch_bounds__(BLOCK)
__global__ void giou_kernel(const float* __restrict__ pred,
                            const float* __restrict__ target,
                            const float* __restrict__ weight,
                            float* __restrict__ out, int N) {
    __shared__ float2 sb[NSLOT][BLOCK];   // 16*256*8 = 32768 B -> 5 blocks/CU

    int tid = threadIdx.x;
    long gi = (long)blockIdx.x * BLOCK + tid;
    int i = (gi < (long)N) ? (int)gi : (N - 1);

    float p[5], q[5];
#pragma unroll
    for (int j = 0; j < 5; ++j) p[j] = pred[i * 5 + j];
#pragma unroll
    for (int j = 0; j < 5; ++j) q[j] = target[i * 5 + j];
    float wgt = weight[i];

    const float dxs[4] = {0.5f, -0.5f, -0.5f, 0.5f};
    const float dys[4] = {0.5f, 0.5f, -0.5f, -0.5f};
    float px[24], py[24];
    {
        float sn, cs;
        sincosf(p[4], &sn, &cs);
#pragma unroll
        for (int j = 0; j < 4; ++j) {
            float cx = dxs[j] * p[2], cy = dys[j] * p[3];
            px[j] = cx * cs - cy * sn + p[0];
            py[j] = cx * sn + cy * cs + p[1];
        }
        sincosf(q[4], &sn, &cs);
#pragma unroll
        for (int j = 0; j < 4; ++j) {
            float cx = dxs[j] * q[2], cy = dys[j] * q[3];
            px[4 + j] = cx * cs - cy * sn + q[0];
            py[4 + j] = cx * sn + cy * cs + q[1];
        }
    }

    unsigned vmask = 0;
    // m1: corners of box1 inside box2 (bits 0..3)
    {
        float ax = px[4], ay = py[4];
        float abx = px[5] - ax, aby = py[5] - ay;
        float adx = px[7] - ax, ady = py[7] - ay;
        float rab = fast_rcp(abx * abx + aby * aby);
        float rad = fast_rcp(adx * adx + ady * ady);
#pragma unroll
        for (int j = 0; j < 4; ++j) {
            float amx = px[j] - ax, amy = py[j] - ay;
            float pab = (amx * abx + amy * aby) * rab;
            float pad = (amx * adx + amy * ady) * rad;
            bool in = (pab > -1e-6f) && (pab < 1.f + 1e-6f) &&
                      (pad > -1e-6f) && (pad < 1.f + 1e-6f);
            vmask |= ((unsigned)in) << j;
        }
    }
    // m2: corners of box2 inside box1 (bits 4..7)
    {
        float ax = px[0], ay = py[0];
        float abx = px[1] - ax, aby = py[1] - ay;
        float adx = px[3] - ax, ady = py[3] - ay;
        float rab = fast_rcp(abx * abx + aby * aby);
        float rad = fast_rcp(adx * adx + ady * ady);
#pragma unroll
        for (int j = 0; j < 4; ++j) {
            float amx = px[4 + j] - ax, amy = py[4 + j] - ay;
            float pab = (amx * abx + amy * aby) * rab;
            float pad = (amx * adx + amy * ady) * rad;
            bool in = (pab > -1e-6f) && (pab < 1.f + 1e-6f) &&
                      (pad > -1e-6f) && (pad < 1.f + 1e-6f);
            vmask |= ((unsigned)in) << (4 + j);
        }
    }

    // edge-pair intersections (bits 8..23)
#pragma unroll
    for (int j = 0; j < 4; ++j) {
        float x1 = px[j], y1 = py[j];
        float x2 = px[(j + 1) & 3], y2 = py[(j + 1) & 3];
#pragma unroll
        for (int k = 0; k < 4; ++k) {
            float x3 = px[4 + k], y3 = py[4 + k];
            float x4 = px[4 + ((k + 1) & 3)], y4 = py[4 + ((k + 1) & 3)];
            float den = (x2 - x1) * (y4 - y3) - (y2 - y1) * (x4 - x3);
            float rden = fast_rcp((den == 0.f) ? 1.f : den);
            float t = ((x3 - x1) * (y4 - y3) - (y3 - y1) * (x4 - x3)) * rden;
            float u = ((x3 - x1) * (y2 - y1) - (y3 - y1) * (x2 - x1)) * rden;
            bool m = (den != 0.f) && (t > 0.f) && (t < 1.f) && (u > 0.f) && (u < 1.f);
            int idx = 8 + j * 4 + k;
            px[idx] = m ? (x1 + t * (x2 - x1)) : 0.f;
            py[idx] = m ? (y1 + t * (y2 - y1)) : 0.f;
            vmask |= ((unsigned)m) << idx;
        }
    }

    int cnt = __popc(vmask);

    // masked mean (same sequential accumulation order as reference concat)
    float sxs = 0.f, sys = 0.f;
#pragma unroll
    for (int j = 0; j < 24; ++j) {
        bool v = (vmask >> j) & 1u;
        sxs += v ? px[j] : 0.f;
        sys += v ? py[j] : 0.f;
    }
    float num = fmaxf((float)cnt, 1.f);
    float mx = sxs / num, my = sys / num;

    float overlap = sorted_area<24, NSLOT>(px, py, vmask, cnt, mx, my, sb, tid);

    float area1 = p[2] * p[3];
    float area2 = q[2] * q[3];
    float uni = area1 + area2 - overlap + 1e-6f;
    float iou = fmaxf(overlap / uni, 1e-6f);

    // enclose: 8 corners, all valid; mean = sum/8 exactly
    float ex = 0.f, ey = 0.f;
#pragma unroll
    for (int j = 0; j < 8; ++j) { ex += px[j]; ey += py[j]; }
    float enc = sorted_area<8, 8>(px, py, 0xFFu, 8, ex * 0.125f, ey * 0.125f, sb, tid);

    float giou = iou - (enc - uni) / enc;
    float loss = (1.f - giou) * wgt;
    if (gi >= (long)N) loss = 0.f;

    // wave-64 reduce, one atomic per wave
#pragma unroll
    for (int off = 32; off > 0; off >>= 1)
        loss += __shfl_down(loss, off, 64);
    if ((tid & 63) == 0)
        atomicAdd(out, loss * (1.0f / (float)N));
}

extern "C" void kernel_launch(void* const* d_in, const int* in_sizes, int n_in,
                              void* d_out, int out_size, void* d_ws, size_t ws_size,
                              hipStream_t stream) {
    const float* pred   = (const float*)d_in[0];
    const float* target = (const float*)d_in[1];
    const float* weight = (const float*)d_in[2];
    float* out = (float*)d_out;
    int N = in_sizes[0] / 5;

    zero_kernel<<<1, 64, 0, stream>>>(out);
    int nblocks = (N + BLOCK - 1) / BLOCK;
    giou_kernel<<<nblocks, BLOCK, 0, stream>>>(pred, target, weight, out, N);
}

// Round 3
// 170.496 us; speedup vs baseline: 1.0974x; 1.0374x over previous
//
#include <hip/hip_runtime.h>
#include <math.h>

#define BLOCK 128
#define NS 8   // slots per ping-pong buffer (max clipped-poly verts = 8)

__global__ void zero_kernel(float* out) {
    if (threadIdx.x == 0 && blockIdx.x == 0) out[0] = 0.0f;
}

__device__ __forceinline__ float fast_rcp(float x) {
    return __builtin_amdgcn_rcpf(x);   // v_rcp_f32; ordering/param paths only
}

// L1 "diamond" pseudo-angle: strictly monotone in atan2(y,x); (0,0) -> 0.
__device__ __forceinline__ float pseudo_angle(float x, float y) {
    float d = fabsf(x) + fabsf(y);
    float p = (d == 0.f) ? 1.f : x * fast_rcp(d);
    return (y < 0.f) ? (p - 1.f) : (1.f - p);
}

__launch_bounds__(BLOCK)
__global__ void giou_kernel(const float* __restrict__ pred,
                            const float* __restrict__ target,
                            const float* __restrict__ weight,
                            float* __restrict__ out, int N) {
    // per-thread private slots, slot-major: bank = (2*tid)%32, conflict-free,
    // no cross-thread sharing -> no __syncthreads needed anywhere.
    __shared__ float2 bufA[NS][BLOCK];   // 8 KiB
    __shared__ float2 bufB[NS][BLOCK];   // 8 KiB  (16 KiB total -> 10 blocks/CU)

    int tid = threadIdx.x;
    long gi = (long)blockIdx.x * BLOCK + tid;
    int i = (gi < (long)N) ? (int)gi : (N - 1);

    float p[5], q[5];
#pragma unroll
    for (int j = 0; j < 5; ++j) p[j] = pred[i * 5 + j];
#pragma unroll
    for (int j = 0; j < 5; ++j) q[j] = target[i * 5 + j];
    float wgt = weight[i];

    // corners (CCW): dx=[.5,-.5,-.5,.5], dy=[.5,.5,-.5,-.5]
    const float dxs[4] = {0.5f, -0.5f, -0.5f, 0.5f};
    const float dys[4] = {0.5f, 0.5f, -0.5f, -0.5f};
    float c1x[4], c1y[4], c2x[4], c2y[4];
    {
        float sn, cs;
        sincosf(p[4], &sn, &cs);
#pragma unroll
        for (int j = 0; j < 4; ++j) {
            float cx = dxs[j] * p[2], cy = dys[j] * p[3];
            c1x[j] = cx * cs - cy * sn + p[0];
            c1y[j] = cx * sn + cy * cs + p[1];
        }
        sincosf(q[4], &sn, &cs);
#pragma unroll
        for (int j = 0; j < 4; ++j) {
            float cx = dxs[j] * q[2], cy = dys[j] * q[3];
            c2x[j] = cx * cs - cy * sn + q[0];
            c2y[j] = cx * sn + cy * cs + q[1];
        }
    }

    // ---------------- overlap via slab Sutherland-Hodgman ----------------
    // Boxes are CCW; inside(edge a->b) = cross(b-a, p-a) >= 0.
    // Slab 1: lines of edge0 (c2[0]->c2[1]) and edge2 (c2[2]->c2[3]) (parallel).
    // Key fact: every point on one slab line satisfies the other constraint
    // (parallel lines, slab width = box extent > 0), so crossings are always
    // region-boundary points and plain in-order emission is valid.
    int m1 = 0;
    {
        float e0x = c2x[1] - c2x[0], e0y = c2y[1] - c2y[0];
        float e2x = c2x[3] - c2x[2], e2y = c2y[3] - c2y[2];
        float sA[4], sB[4];
#pragma unroll
        for (int j = 0; j < 4; ++j) {
            sA[j] = e0x * (c1y[j] - c2y[0]) - e0y * (c1x[j] - c2x[0]);
            sB[j] = e2x * (c1y[j] - c2y[2]) - e2y * (c1x[j] - c2x[2]);
        }
#pragma unroll
        for (int e = 0; e < 4; ++e) {
            int en = (e + 1) & 3;
            float cx = c1x[e], cy = c1y[e];
            float dx = c1x[en] - cx, dy = c1y[en] - cy;
            float sac = sA[e], san = sA[en];
            float sbc = sB[e], sbn = sB[en];
            bool inC = (sac >= 0.f) && (sbc >= 0.f);
            bool cA = (sac >= 0.f) != (san >= 0.f);
            bool cB = (sbc >= 0.f) != (sbn >= 0.f);
            float tA = sac * fast_rcp(sac - san);
            float tB = sbc * fast_rcp(sbc - sbn);
            float XAx = fmaf(tA, dx, cx), XAy = fmaf(tA, dy, cy);
            float XBx = fmaf(tB, dx, cx), XBy = fmaf(tB, dy, cy);
            if (inC) { bufA[m1][tid] = make_float2(cx, cy); m1++; }
            bool fA = cA && (!cB || (tA <= tB));
            float X1x = fA ? XAx : XBx, X1y = fA ? XAy : XBy;
            float X2x = fA ? XBx : XAx, X2y = fA ? XBy : XAy;
            if (cA || cB) { bufA[m1][tid] = make_float2(X1x, X1y); m1++; }
            if (cA && cB) { bufA[m1][tid] = make_float2(X2x, X2y); m1++; }
        }
    }
    int n1 = (m1 < 6) ? m1 : 6;   // convex quad clipped by 2 lines: <= 6 verts

    // Slab 2: lines of edge1 (c2[1]->c2[2]) and edge3 (c2[3]->c2[0]).
    int m2 = 0;
    {
        float e1x = c2x[2] - c2x[1], e1y = c2y[2] - c2y[1];
        float e3x = c2x[0] - c2x[3], e3y = c2y[0] - c2y[3];
        float vx[6], vy[6], s1[6], s3[6];
#pragma unroll
        for (int j = 0; j < 6; ++j) {
            float2 v = bufA[j][tid];           // slots >= n1 are garbage; masked below
            vx[j] = v.x; vy[j] = v.y;
            s1[j] = e1x * (v.y - c2y[1]) - e1y * (v.x - c2x[1]);
            s3[j] = e3x * (v.y - c2y[3]) - e3y * (v.x - c2x[3]);
        }
#pragma unroll
        for (int e = 0; e < 6; ++e) {
            bool act = (e < n1);
            bool last = (e == n1 - 1);
            int en = (e + 1 < 6) ? e + 1 : 0;  // static; wrap handled via `last`
            float nx = last ? vx[0] : vx[en];
            float ny = last ? vy[0] : vy[en];
            float san = last ? s1[0] : s1[en];
            float sbn = last ? s3[0] : s3[en];
            float cx = vx[e], cy = vy[e];
            float dx = nx - cx, dy = ny - cy;
            float sac = s1[e], sbc = s3[e];
            bool inC = (sac >= 0.f) && (sbc >= 0.f);
            bool cA = (sac >= 0.f) != (san >= 0.f);
            bool cB = (sbc >= 0.f) != (sbn >= 0.f);
            float tA = sac * fast_rcp(sac - san);
            float tB = sbc * fast_rcp(sbc - sbn);
            float XAx = fmaf(tA, dx, cx), XAy = fmaf(tA, dy, cy);
            float XBx = fmaf(tB, dx, cx), XBy = fmaf(tB, dy, cy);
            if (act && inC && m2 < NS) { bufB[m2][tid] = make_float2(cx, cy); m2++; }
            bool fA = cA && (!cB || (tA <= tB));
            float X1x = fA ? XAx : XBx, X1y = fA ? XAy : XBy;
            float X2x = fA ? XBx : XAx, X2y = fA ? XBy : XAy;
            if (act && (cA || cB) && m2 < NS) { bufB[m2][tid] = make_float2(X1x, X1y); m2++; }
            if (act && cA && cB && m2 < NS) { bufB[m2][tid] = make_float2(X2x, X2y); m2++; }
        }
    }
    int n2 = (m2 < NS) ? m2 : NS;

    // shoelace of clipped polygon; slots >= n2 act as vertex 0
    float overlap;
    {
        float fx[8], fy[8];
#pragma unroll
        for (int k = 0; k < 8; ++k) {
            float2 v = bufB[k][tid];
            fx[k] = v.x; fy[k] = v.y;
        }
#pragma unroll
        for (int k = 1; k < 8; ++k) {
            bool u = (k < n2);
            fx[k] = u ? fx[k] : fx[0];
            fy[k] = u ? fy[k] : fy[0];
        }
        float acc = 0.f;
#pragma unroll
        for (int k = 0; k < 8; ++k) {
            int kn = (k + 1) & 7;
            acc += fx[k] * fy[kn] - fy[k] * fx[kn];
        }
        overlap = 0.5f * fabsf(acc);
        overlap = (n2 >= 3) ? overlap : 0.f;   // select: kills any garbage NaN too
    }

    // ---------------- enclose: 8 corners, reference-faithful sorted shoelace ----
    float enc;
    {
        float px[8], py[8];
#pragma unroll
        for (int j = 0; j < 4; ++j) {
            px[j] = c1x[j];     py[j] = c1y[j];
            px[4 + j] = c2x[j]; py[4 + j] = c2y[j];
        }
        float ex = 0.f, ey = 0.f;
#pragma unroll
        for (int j = 0; j < 8; ++j) { ex += px[j]; ey += py[j]; }
        float mx = ex * 0.125f, my = ey * 0.125f;
        float ang[8];
#pragma unroll
        for (int j = 0; j < 8; ++j) ang[j] = pseudo_angle(px[j] - mx, py[j] - my);
        // stable rank (angle, index) -> scatter into bufA (reused; same-thread
        // program order guarantees prior reads completed before these writes)
#pragma unroll
        for (int j = 0; j < 8; ++j) {
            int r = 0;
#pragma unroll
            for (int k = 0; k < 8; ++k) {
                if (k < j)      r += (ang[k] <= ang[j]) ? 1 : 0;
                else if (k > j) r += (ang[k] <  ang[j]) ? 1 : 0;
            }
            bufA[r][tid] = make_float2(px[j], py[j]);
        }
        float sx0[8], sy0[8];
#pragma unroll
        for (int k = 0; k < 8; ++k) {
            float2 v = bufA[k][tid];
            sx0[k] = v.x; sy0[k] = v.y;
        }
        float acc = 0.f;
#pragma unroll
        for (int k = 0; k < 8; ++k) {
            int kn = (k + 1) & 7;
            acc += sx0[k] * sy0[kn] - sy0[k] * sx0[kn];
        }
        enc = 0.5f * fabsf(acc);
    }

    // ---------------- GIoU loss ----------------
    float area1 = p[2] * p[3];
    float area2 = q[2] * q[3];
    float uni = area1 + area2 - overlap + 1e-6f;
    float iou = fmaxf(overlap / uni, 1e-6f);
    float giou = iou - (enc - uni) / enc;
    float loss = (1.f - giou) * wgt;
    if (gi >= (long)N) loss = 0.f;

    // wave-64 reduce, one atomic per wave
#pragma unroll
    for (int off = 32; off > 0; off >>= 1)
        loss += __shfl_down(loss, off, 64);
    if ((tid & 63) == 0)
        atomicAdd(out, loss * (1.0f / (float)N));
}

extern "C" void kernel_launch(void* const* d_in, const int* in_sizes, int n_in,
                              void* d_out, int out_size, void* d_ws, size_t ws_size,
                              hipStream_t stream) {
    const float* pred   = (const float*)d_in[0];
    const float* target = (const float*)d_in[1];
    const float* weight = (const float*)d_in[2];
    float* out = (float*)d_out;
    int N = in_sizes[0] / 5;

    zero_kernel<<<1, 64, 0, stream>>>(out);
    int nblocks = (N + BLOCK - 1) / BLOCK;
    giou_kernel<<<nblocks, BLOCK, 0, stream>>>(pred, target, weight, out, N);
}

// Round 4
// 89.074 us; speedup vs baseline: 2.1005x; 1.9141x over previous
//
#include <hip/hip_runtime.h>
#include <math.h>

#define BLOCK 128
#define NS 8   // slots per ping-pong buffer (max clipped-poly verts = 8)

__device__ __forceinline__ float fast_rcp(float x) {
    return __builtin_amdgcn_rcpf(x);   // v_rcp_f32; ordering/param paths only
}

// L1 "diamond" pseudo-angle: strictly monotone in atan2(y,x); (0,0) -> 0.
__device__ __forceinline__ float pseudo_angle(float x, float y) {
    float d = fabsf(x) + fabsf(y);
    float p = (d == 0.f) ? 1.f : x * fast_rcp(d);
    return (y < 0.f) ? (p - 1.f) : (1.f - p);
}

__launch_bounds__(BLOCK)
__global__ void giou_kernel(const float* __restrict__ pred,
                            const float* __restrict__ target,
                            const float* __restrict__ weight,
                            float* __restrict__ partials, int N) {
    // per-thread private slots, slot-major: bank = (2*tid)%32, conflict-free,
    // no cross-thread sharing -> no __syncthreads needed anywhere.
    __shared__ float2 bufA[NS][BLOCK];   // 8 KiB
    __shared__ float2 bufB[NS][BLOCK];   // 8 KiB  (16 KiB total -> 10 blocks/CU)

    int tid = threadIdx.x;
    long gi = (long)blockIdx.x * BLOCK + tid;
    int i = (gi < (long)N) ? (int)gi : (N - 1);

    float p[5], q[5];
#pragma unroll
    for (int j = 0; j < 5; ++j) p[j] = pred[i * 5 + j];
#pragma unroll
    for (int j = 0; j < 5; ++j) q[j] = target[i * 5 + j];
    float wgt = weight[i];

    // corners (CCW): dx=[.5,-.5,-.5,.5], dy=[.5,.5,-.5,-.5]
    const float dxs[4] = {0.5f, -0.5f, -0.5f, 0.5f};
    const float dys[4] = {0.5f, 0.5f, -0.5f, -0.5f};
    float c1x[4], c1y[4], c2x[4], c2y[4];
    {
        float sn, cs;
        sincosf(p[4], &sn, &cs);
#pragma unroll
        for (int j = 0; j < 4; ++j) {
            float cx = dxs[j] * p[2], cy = dys[j] * p[3];
            c1x[j] = cx * cs - cy * sn + p[0];
            c1y[j] = cx * sn + cy * cs + p[1];
        }
        sincosf(q[4], &sn, &cs);
#pragma unroll
        for (int j = 0; j < 4; ++j) {
            float cx = dxs[j] * q[2], cy = dys[j] * q[3];
            c2x[j] = cx * cs - cy * sn + q[0];
            c2y[j] = cx * sn + cy * cs + q[1];
        }
    }

    // ---------------- overlap via slab Sutherland-Hodgman ----------------
    // Boxes are CCW; inside(edge a->b) = cross(b-a, p-a) >= 0.
    // Slab 1: lines of edge0 (c2[0]->c2[1]) and edge2 (c2[2]->c2[3]) (parallel).
    int m1 = 0;
    {
        float e0x = c2x[1] - c2x[0], e0y = c2y[1] - c2y[0];
        float e2x = c2x[3] - c2x[2], e2y = c2y[3] - c2y[2];
        float sA[4], sB[4];
#pragma unroll
        for (int j = 0; j < 4; ++j) {
            sA[j] = e0x * (c1y[j] - c2y[0]) - e0y * (c1x[j] - c2x[0]);
            sB[j] = e2x * (c1y[j] - c2y[2]) - e2y * (c1x[j] - c2x[2]);
        }
#pragma unroll
        for (int e = 0; e < 4; ++e) {
            int en = (e + 1) & 3;
            float cx = c1x[e], cy = c1y[e];
            float dx = c1x[en] - cx, dy = c1y[en] - cy;
            float sac = sA[e], san = sA[en];
            float sbc = sB[e], sbn = sB[en];
            bool inC = (sac >= 0.f) && (sbc >= 0.f);
            bool cA = (sac >= 0.f) != (san >= 0.f);
            bool cB = (sbc >= 0.f) != (sbn >= 0.f);
            float tA = sac * fast_rcp(sac - san);
            float tB = sbc * fast_rcp(sbc - sbn);
            float XAx = fmaf(tA, dx, cx), XAy = fmaf(tA, dy, cy);
            float XBx = fmaf(tB, dx, cx), XBy = fmaf(tB, dy, cy);
            if (inC) { bufA[m1][tid] = make_float2(cx, cy); m1++; }
            bool fA = cA && (!cB || (tA <= tB));
            float X1x = fA ? XAx : XBx, X1y = fA ? XAy : XBy;
            float X2x = fA ? XBx : XAx, X2y = fA ? XBy : XAy;
            if (cA || cB) { bufA[m1][tid] = make_float2(X1x, X1y); m1++; }
            if (cA && cB) { bufA[m1][tid] = make_float2(X2x, X2y); m1++; }
        }
    }
    int n1 = (m1 < 6) ? m1 : 6;   // convex quad clipped by 2 lines: <= 6 verts

    // Slab 2: lines of edge1 (c2[1]->c2[2]) and edge3 (c2[3]->c2[0]).
    int m2 = 0;
    {
        float e1x = c2x[2] - c2x[1], e1y = c2y[2] - c2y[1];
        float e3x = c2x[0] - c2x[3], e3y = c2y[0] - c2y[3];
        float vx[6], vy[6], s1[6], s3[6];
#pragma unroll
        for (int j = 0; j < 6; ++j) {
            float2 v = bufA[j][tid];           // slots >= n1 are garbage; masked below
            vx[j] = v.x; vy[j] = v.y;
            s1[j] = e1x * (v.y - c2y[1]) - e1y * (v.x - c2x[1]);
            s3[j] = e3x * (v.y - c2y[3]) - e3y * (v.x - c2x[3]);
        }
#pragma unroll
        for (int e = 0; e < 6; ++e) {
            bool act = (e < n1);
            bool last = (e == n1 - 1);
            int en = (e + 1 < 6) ? e + 1 : 0;  // static; wrap handled via `last`
            float nx = last ? vx[0] : vx[en];
            float ny = last ? vy[0] : vy[en];
            float san = last ? s1[0] : s1[en];
            float sbn = last ? s3[0] : s3[en];
            float cx = vx[e], cy = vy[e];
            float dx = nx - cx, dy = ny - cy;
            float sac = s1[e], sbc = s3[e];
            bool inC = (sac >= 0.f) && (sbc >= 0.f);
            bool cA = (sac >= 0.f) != (san >= 0.f);
            bool cB = (sbc >= 0.f) != (sbn >= 0.f);
            float tA = sac * fast_rcp(sac - san);
            float tB = sbc * fast_rcp(sbc - sbn);
            float XAx = fmaf(tA, dx, cx), XAy = fmaf(tA, dy, cy);
            float XBx = fmaf(tB, dx, cx), XBy = fmaf(tB, dy, cy);
            if (act && inC && m2 < NS) { bufB[m2][tid] = make_float2(cx, cy); m2++; }
            bool fA = cA && (!cB || (tA <= tB));
            float X1x = fA ? XAx : XBx, X1y = fA ? XAy : XBy;
            float X2x = fA ? XBx : XAx, X2y = fA ? XBy : XAy;
            if (act && (cA || cB) && m2 < NS) { bufB[m2][tid] = make_float2(X1x, X1y); m2++; }
            if (act && cA && cB && m2 < NS) { bufB[m2][tid] = make_float2(X2x, X2y); m2++; }
        }
    }
    int n2 = (m2 < NS) ? m2 : NS;

    // shoelace of clipped polygon; slots >= n2 act as vertex 0
    float overlap;
    {
        float fx[8], fy[8];
#pragma unroll
        for (int k = 0; k < 8; ++k) {
            float2 v = bufB[k][tid];
            fx[k] = v.x; fy[k] = v.y;
        }
#pragma unroll
        for (int k = 1; k < 8; ++k) {
            bool u = (k < n2);
            fx[k] = u ? fx[k] : fx[0];
            fy[k] = u ? fy[k] : fy[0];
        }
        float acc = 0.f;
#pragma unroll
        for (int k = 0; k < 8; ++k) {
            int kn = (k + 1) & 7;
            acc += fx[k] * fy[kn] - fy[k] * fx[kn];
        }
        overlap = 0.5f * fabsf(acc);
        overlap = (n2 >= 3) ? overlap : 0.f;   // select: kills any garbage NaN too
    }

    // ---------------- enclose: 8 corners, reference-faithful sorted shoelace ----
    float enc;
    {
        float px[8], py[8];
#pragma unroll
        for (int j = 0; j < 4; ++j) {
            px[j] = c1x[j];     py[j] = c1y[j];
            px[4 + j] = c2x[j]; py[4 + j] = c2y[j];
        }
        float ex = 0.f, ey = 0.f;
#pragma unroll
        for (int j = 0; j < 8; ++j) { ex += px[j]; ey += py[j]; }
        float mx = ex * 0.125f, my = ey * 0.125f;
        float ang[8];
#pragma unroll
        for (int j = 0; j < 8; ++j) ang[j] = pseudo_angle(px[j] - mx, py[j] - my);
        // stable rank (angle, index) -> scatter into bufA (reused; same-thread
        // program order guarantees prior reads completed before these writes)
#pragma unroll
        for (int j = 0; j < 8; ++j) {
            int r = 0;
#pragma unroll
            for (int k = 0; k < 8; ++k) {
                if (k < j)      r += (ang[k] <= ang[j]) ? 1 : 0;
                else if (k > j) r += (ang[k] <  ang[j]) ? 1 : 0;
            }
            bufA[r][tid] = make_float2(px[j], py[j]);
        }
        float sx0[8], sy0[8];
#pragma unroll
        for (int k = 0; k < 8; ++k) {
            float2 v = bufA[k][tid];
            sx0[k] = v.x; sy0[k] = v.y;
        }
        float acc = 0.f;
#pragma unroll
        for (int k = 0; k < 8; ++k) {
            int kn = (k + 1) & 7;
            acc += sx0[k] * sy0[kn] - sy0[k] * sx0[kn];
        }
        enc = 0.5f * fabsf(acc);
    }

    // ---------------- GIoU loss ----------------
    float area1 = p[2] * p[3];
    float area2 = q[2] * q[3];
    float uni = area1 + area2 - overlap + 1e-6f;
    float iou = fmaxf(overlap / uni, 1e-6f);
    float giou = iou - (enc - uni) / enc;
    float loss = (1.f - giou) * wgt;
    if (gi >= (long)N) loss = 0.f;

    // wave-64 reduce -> ONE PLAIN STORE per wave (no global atomics: 7813
    // same-address atomics were serializing at ~13.6 ns each = the 100 us floor)
#pragma unroll
    for (int off = 32; off > 0; off >>= 1)
        loss += __shfl_down(loss, off, 64);
    if ((tid & 63) == 0)
        partials[blockIdx.x * (BLOCK / 64) + (tid >> 6)] = loss;
}

// Deterministic final reduce: one block, grid-stride over partials.
__launch_bounds__(256)
__global__ void reduce_kernel(const float* __restrict__ partials,
                              float* __restrict__ out, int nparts, float scale) {
    __shared__ float acc[4];
    int tid = threadIdx.x;
    float s = 0.f;
    for (int j = tid; j < nparts; j += 256) s += partials[j];
#pragma unroll
    for (int off = 32; off > 0; off >>= 1)
        s += __shfl_down(s, off, 64);
    if ((tid & 63) == 0) acc[tid >> 6] = s;
    __syncthreads();
    if (tid == 0) out[0] = (acc[0] + acc[1] + acc[2] + acc[3]) * scale;
}

extern "C" void kernel_launch(void* const* d_in, const int* in_sizes, int n_in,
                              void* d_out, int out_size, void* d_ws, size_t ws_size,
                              hipStream_t stream) {
    const float* pred   = (const float*)d_in[0];
    const float* target = (const float*)d_in[1];
    const float* weight = (const float*)d_in[2];
    float* out = (float*)d_out;
    float* ws  = (float*)d_ws;
    int N = in_sizes[0] / 5;

    int nblocks = (N + BLOCK - 1) / BLOCK;
    int nparts = nblocks * (BLOCK / 64);
    giou_kernel<<<nblocks, BLOCK, 0, stream>>>(pred, target, weight, ws, N);
    reduce_kernel<<<1, 256, 0, stream>>>(ws, out, nparts, 1.0f / (float)N);
}

// Round 5
// 80.594 us; speedup vs baseline: 2.3215x; 1.1052x over previous
//
#include <hip/hip_runtime.h>
#include <math.h>

#define BLOCK 128

__device__ __forceinline__ float fast_rcp(float x) {
    return __builtin_amdgcn_rcpf(x);
}
// HW sin/cos: v_sin_f32/v_cos_f32 take revolutions; |arg| < 1 rev here -> full accuracy
__device__ __forceinline__ float fsin(float x) {
    return __builtin_amdgcn_sinf(x * 0.15915494309189535f);
}
__device__ __forceinline__ float fcos(float x) {
    return __builtin_amdgcn_cosf(x * 0.15915494309189535f);
}

// L1 "diamond" pseudo-angle: strictly monotone in atan2(y,x); (0,0) -> 0.
__device__ __forceinline__ float pseudo_angle(float x, float y) {
    float d = fabsf(x) + fabsf(y);
    float p = (d == 0.f) ? 1.f : x * fast_rcp(d);
    return (y < 0.f) ? (p - 1.f) : (1.f - p);
}

// Running-shoelace state: first point, prev point, accumulator.
struct Shoe {
    float sfx, sfy, spx, spy, acc;
    bool have;
};

__device__ __forceinline__ void emit(Shoe& s, bool c, float X, float Y) {
    float cr = s.spx * Y - s.spy * X;
    s.acc += (c && s.have) ? cr : 0.f;
    s.sfx = (c && !s.have) ? X : s.sfx;
    s.sfy = (c && !s.have) ? Y : s.sfy;
    s.spx = c ? X : s.spx;
    s.spy = c ? Y : s.spy;
    s.have = s.have || c;
}

// SH edge (a->b) clipped against y in [-hh, hh], emissions into running shoelace.
// All garbage values (rcp(0) etc.) sit behind false selects.
__device__ __forceinline__ void edge_clip_y(Shoe& s, bool en, float ax, float ay,
                                            float bx, float by, float hh) {
    bool inA = en && (ay <= hh) && (ay >= -hh);
    bool cA = en && ((ay > hh) != (by > hh));
    bool cB = en && ((ay < -hh) != (by < -hh));
    float dxe = bx - ax, dye = by - ay;
    float rd = fast_rcp(dye);
    float tA = (hh - ay) * rd;
    float tB = (-hh - ay) * rd;
    float xA = fmaf(tA, dxe, ax);
    float xB = fmaf(tB, dxe, ax);
    bool fA = cA && (!cB || (tA <= tB));
    float e1x = fA ? xA : xB, e1y = fA ? hh : -hh;
    float e2x = fA ? xB : xA, e2y = fA ? -hh : hh;
    emit(s, inA, ax, ay);
    emit(s, cA || cB, e1x, e1y);
    emit(s, cA && cB, e2x, e2y);
}

__launch_bounds__(BLOCK)
__global__ void giou_kernel(const float* __restrict__ pred,
                            const float* __restrict__ target,
                            const float* __restrict__ weight,
                            float* __restrict__ partials, int N) {
    // enclose-sort scratch only; per-thread slots, slot-major -> conflict-free
    __shared__ float2 bufA[8][BLOCK];   // 8 KiB

    int tid = threadIdx.x;
    long gi = (long)blockIdx.x * BLOCK + tid;
    int i = (gi < (long)N) ? (int)gi : (N - 1);

    float p[5], q[5];
#pragma unroll
    for (int j = 0; j < 5; ++j) p[j] = pred[i * 5 + j];
#pragma unroll
    for (int j = 0; j < 5; ++j) q[j] = target[i * 5 + j];
    float wgt = weight[i];

    // ---- everything in box2's local frame (areas are rotation-invariant) ----
    float cq = fcos(q[4]), sq = fsin(q[4]);
    float dang = p[4] - q[4];
    float cd = fcos(dang), sd = fsin(dang);
    float hw = 0.5f * q[2], hh = 0.5f * q[3];   // box2 = [-hw,hw]x[-hh,hh]
    float dxc = p[0] - q[0], dyc = p[1] - q[1];
    float tx = dxc * cq + dyc * sq;
    float ty = -dxc * sq + dyc * cq;
    float ax_ = 0.5f * p[2] * cd, ay_ = 0.5f * p[2] * sd;   // 0.5*w1*(cd,sd)
    float bx_ = -0.5f * p[3] * sd, by_ = 0.5f * p[3] * cd;  // 0.5*h1*(-sd,cd)

    // box1 corners in frame, CCW, same (dx,dy) pattern as reference
    float qx[4], qy[4];
    qx[0] = tx + ax_ + bx_; qy[0] = ty + ay_ + by_;
    qx[1] = tx - ax_ + bx_; qy[1] = ty - ay_ + by_;
    qx[2] = tx - ax_ - bx_; qy[2] = ty - ay_ - by_;
    qx[3] = tx + ax_ - bx_; qy[3] = ty + ay_ - by_;

    // ---- slab 1: clip quad against x in [-hw, hw] -> 8 fixed slots ----
    // each edge emits at most 2 points (inside-vertex + <=1 crossing, or 2 crossings)
    float sxk[8], syk[8];
    bool sv[8];
#pragma unroll
    for (int e = 0; e < 4; ++e) {
        int en = (e + 1) & 3;
        float xc = qx[e], yc = qy[e], xn = qx[en], yn = qy[en];
        float dxe = xn - xc, dye = yn - yc;
        bool inC = (xc <= hw) && (xc >= -hw);
        bool cA = (xc > hw) != (xn > hw);
        bool cB = (xc < -hw) != (xn < -hw);
        float rd = fast_rcp(dxe);
        float tA = (hw - xc) * rd;
        float tB = (-hw - xc) * rd;
        float yA = fmaf(tA, dye, yc);
        float yB = fmaf(tB, dye, yc);
        bool fA = cA && (!cB || (tA <= tB));
        float X1x = fA ? hw : -hw, X1y = fA ? yA : yB;
        float X2x = fA ? -hw : hw, X2y = fA ? yB : yA;
        sxk[2 * e]     = inC ? xc : X1x;
        syk[2 * e]     = inC ? yc : X1y;
        sv[2 * e]      = inC || cA || cB;
        sxk[2 * e + 1] = inC ? X1x : X2x;
        syk[2 * e + 1] = inC ? X1y : X2y;
        sv[2 * e + 1]  = inC ? (cA || cB) : (cA && cB);
    }

    // ---- slab 2 (y in [-hh,hh]) fused with running shoelace, all registers ----
    Shoe sh; sh.sfx = sh.sfy = sh.spx = sh.spy = sh.acc = 0.f; sh.have = false;
    bool have_p = false;
    float pfx = 0.f, pfy = 0.f, pvx = 0.f, pvy = 0.f;
#pragma unroll
    for (int k = 0; k < 8; ++k) {
        bool val = sv[k];
        float cx_ = sxk[k], cy_ = syk[k];
        edge_clip_y(sh, have_p && val, pvx, pvy, cx_, cy_, hh);
        pfx = (val && !have_p) ? cx_ : pfx;
        pfy = (val && !have_p) ? cy_ : pfy;
        pvx = val ? cx_ : pvx;
        pvy = val ? cy_ : pvy;
        have_p = have_p || val;
    }
    edge_clip_y(sh, have_p, pvx, pvy, pfx, pfy, hh);   // wrap edge (last -> first)
    float wrap = sh.spx * sh.sfy - sh.spy * sh.sfx;    // close shoelace
    float accs = sh.acc + (sh.have ? wrap : 0.f);
    float overlap = 0.5f * fabsf(accs);

    // ---- enclose: 8 frame points, reference-faithful sorted shoelace ----
    float enc;
    {
        float px8[8], py8[8];
#pragma unroll
        for (int j = 0; j < 4; ++j) { px8[j] = qx[j]; py8[j] = qy[j]; }
        px8[4] = hw;  py8[4] = hh;
        px8[5] = -hw; py8[5] = hh;
        px8[6] = -hw; py8[6] = -hh;
        px8[7] = hw;  py8[7] = -hh;
        float ex = 0.f, ey = 0.f;
#pragma unroll
        for (int j = 0; j < 8; ++j) { ex += px8[j]; ey += py8[j]; }
        float mx = ex * 0.125f, my = ey * 0.125f;
        float ang[8];
#pragma unroll
        for (int j = 0; j < 8; ++j) ang[j] = pseudo_angle(px8[j] - mx, py8[j] - my);
        // stable rank (angle, index) -> per-thread LDS scatter (single round trip)
#pragma unroll
        for (int j = 0; j < 8; ++j) {
            int r = 0;
#pragma unroll
            for (int k = 0; k < 8; ++k) {
                if (k < j)      r += (ang[k] <= ang[j]) ? 1 : 0;
                else if (k > j) r += (ang[k] <  ang[j]) ? 1 : 0;
            }
            bufA[r][tid] = make_float2(px8[j], py8[j]);
        }
        float sx0[8], sy0[8];
#pragma unroll
        for (int k = 0; k < 8; ++k) {
            float2 v = bufA[k][tid];
            sx0[k] = v.x; sy0[k] = v.y;
        }
        float acc2 = 0.f;
#pragma unroll
        for (int k = 0; k < 8; ++k) {
            int kn = (k + 1) & 7;
            acc2 += sx0[k] * sy0[kn] - sy0[k] * sx0[kn];
        }
        enc = 0.5f * fabsf(acc2);
    }

    // ---- GIoU loss ----
    float area1 = p[2] * p[3];
    float area2 = q[2] * q[3];
    float uni = area1 + area2 - overlap + 1e-6f;
    float iou = fmaxf(overlap / uni, 1e-6f);
    float giou = iou - (enc - uni) / enc;
    float loss = (1.f - giou) * wgt;
    if (gi >= (long)N) loss = 0.f;

    // wave-64 reduce -> one plain store per wave (no global atomics)
#pragma unroll
    for (int off = 32; off > 0; off >>= 1)
        loss += __shfl_down(loss, off, 64);
    if ((tid & 63) == 0)
        partials[blockIdx.x * (BLOCK / 64) + (tid >> 6)] = loss;
}

// Deterministic final reduce: one 1024-thread block over the partials.
__launch_bounds__(1024)
__global__ void reduce_kernel(const float* __restrict__ partials,
                              float* __restrict__ out, int nparts, float scale) {
    __shared__ float acc[16];
    int tid = threadIdx.x;
    float s = 0.f;
    for (int j = tid; j < nparts; j += 1024) s += partials[j];
#pragma unroll
    for (int off = 32; off > 0; off >>= 1)
        s += __shfl_down(s, off, 64);
    if ((tid & 63) == 0) acc[tid >> 6] = s;
    __syncthreads();
    if (tid == 0) {
        float t = 0.f;
#pragma unroll
        for (int k = 0; k < 16; ++k) t += acc[k];
        out[0] = t * scale;
    }
}

extern "C" void kernel_launch(void* const* d_in, const int* in_sizes, int n_in,
                              void* d_out, int out_size, void* d_ws, size_t ws_size,
                              hipStream_t stream) {
    const float* pred   = (const float*)d_in[0];
    const float* target = (const float*)d_in[1];
    const float* weight = (const float*)d_in[2];
    float* out = (float*)d_out;
    float* ws  = (float*)d_ws;
    int N = in_sizes[0] / 5;

    int nblocks = (N + BLOCK - 1) / BLOCK;
    int nparts = nblocks * (BLOCK / 64);
    giou_kernel<<<nblocks, BLOCK, 0, stream>>>(pred, target, weight, ws, N);
    reduce_kernel<<<1, 1024, 0, stream>>>(ws, out, nparts, 1.0f / (float)N);
}